// Round 7
// baseline (184.001 us; speedup 1.0000x reference)
//
#include <hip/hip_runtime.h>

#define BB    4
#define NN    8192
#define KK    16
#define CIN   64
#define COUTC 64
#define P     16           // points per MFMA M-tile

typedef short bf16x8 __attribute__((ext_vector_type(8)));
typedef float f32x4  __attribute__((ext_vector_type(4)));

__device__ __forceinline__ unsigned short f2bf_rne(float f) {
    unsigned int u = __builtin_bit_cast(unsigned int, f);
    u += 0x7fffu + ((u >> 16) & 1u);
    return (unsigned short)(u >> 16);
}

__device__ __forceinline__ unsigned int pack_bf2(float lo, float hi) {
    return (unsigned int)f2bf_rne(lo) | ((unsigned int)f2bf_rne(hi) << 16);
}

// Wt[cout][g], g = pass*512 + cin*8 + ml  (logical m = pass*8 + ml), 1/16 folded.
__global__ __launch_bounds__(256) void prep_w(const float* __restrict__ W,
                                              unsigned short* __restrict__ Wt) {
    const int o    = blockIdx.x * 256 + threadIdx.x;   // 65536 total
    const int cout = o >> 10;
    const int g    = o & 1023;
    const int pass = g >> 9;
    const int q    = g & 511;
    const int cin  = q >> 3;
    const int m    = pass * 8 + (q & 7);
    Wt[o] = f2bf_rne(W[(cin * 16 + m) * 64 + cout] * (1.0f / 16.0f));
}

// folded layer-1: A1[j] = {a0,a1,a2,b'} per hidden unit j
__global__ void prep_fold(const float* __restrict__ l1w, const float* __restrict__ l1b,
                          const float* __restrict__ centers, float* __restrict__ A1) {
    const int t = threadIdx.x;     // 32 threads
    float bb = l1b[t];
    float a0 = 0.f, a1 = 0.f, a2 = 0.f;
    for (int c = 0; c < 16; ++c) {
        const float w0 = l1w[(c     ) * 32 + t];
        const float w1 = l1w[(16 + c) * 32 + t];
        const float w2 = l1w[(32 + c) * 32 + t];
        a0 += w0; a1 += w1; a2 += w2;
        bb -= centers[c] * w0 + centers[16 + c] * w1 + centers[32 + c] * w2;
    }
    A1[t * 4 + 0] = a0; A1[t * 4 + 1] = a1; A1[t * 4 + 2] = a2; A1[t * 4 + 3] = bb;
}

// ================= stage A: MLP, one thread per (point, k) =================
__global__ __launch_bounds__(256) void mlp_kernel(
    const float* __restrict__ points, const float* __restrict__ next_pts,
    const int*   __restrict__ indices, const float* __restrict__ A1f,
    const float* __restrict__ l2w, const float* __restrict__ l2b,
    const float* __restrict__ l3w, const float* __restrict__ l3b,
    float* __restrict__ h3g)                 // [B*N*K][16] f32
{
    __shared__ float s_A1[32][4];
    __shared__ float s_w2[32][16];
    __shared__ float s_w3[16][16];
    __shared__ float s_b2[16], s_b3[16];
    const int t = threadIdx.x;
    if (t < 128) ((float*)s_A1)[t] = A1f[t];
    for (int i = t; i < 512; i += 256) ((float*)s_w2)[i] = l2w[i];
    if (t < 256) ((float*)s_w3)[t] = l3w[t];
    if (t < 16)  { s_b2[t] = l2b[t]; s_b3[t] = l3b[t]; }
    __syncthreads();

    const int task = blockIdx.x * 256 + t;   // 524288 total
    const int pt   = task >> 4;
    const int b    = pt >> 13;
    const int id   = indices[task];
    const float* pp = points + ((size_t)(b * NN + id)) * 3;
    const float* np = next_pts + (size_t)pt * 3;
    const float px = pp[0] - np[0];
    const float py = pp[1] - np[1];
    const float pz = pp[2] - np[2];

    float h1[32];
    #pragma unroll
    for (int j = 0; j < 32; ++j) {
        const float4 a = *(const float4*)&s_A1[j][0];
        h1[j] = fmaxf(fmaf(px, a.x, fmaf(py, a.y, fmaf(pz, a.z, a.w))), 0.f);
    }
    float h2[16];
    #pragma unroll
    for (int j = 0; j < 16; ++j) h2[j] = s_b2[j];
    #pragma unroll
    for (int i = 0; i < 32; ++i) {
        const float4 q0 = *(const float4*)&s_w2[i][0];
        const float4 q1 = *(const float4*)&s_w2[i][4];
        const float4 q2 = *(const float4*)&s_w2[i][8];
        const float4 q3 = *(const float4*)&s_w2[i][12];
        h2[0]  = fmaf(h1[i], q0.x, h2[0]);  h2[1]  = fmaf(h1[i], q0.y, h2[1]);
        h2[2]  = fmaf(h1[i], q0.z, h2[2]);  h2[3]  = fmaf(h1[i], q0.w, h2[3]);
        h2[4]  = fmaf(h1[i], q1.x, h2[4]);  h2[5]  = fmaf(h1[i], q1.y, h2[5]);
        h2[6]  = fmaf(h1[i], q1.z, h2[6]);  h2[7]  = fmaf(h1[i], q1.w, h2[7]);
        h2[8]  = fmaf(h1[i], q2.x, h2[8]);  h2[9]  = fmaf(h1[i], q2.y, h2[9]);
        h2[10] = fmaf(h1[i], q2.z, h2[10]); h2[11] = fmaf(h1[i], q2.w, h2[11]);
        h2[12] = fmaf(h1[i], q3.x, h2[12]); h2[13] = fmaf(h1[i], q3.y, h2[13]);
        h2[14] = fmaf(h1[i], q3.z, h2[14]); h2[15] = fmaf(h1[i], q3.w, h2[15]);
    }
    #pragma unroll
    for (int j = 0; j < 16; ++j) h2[j] = fmaxf(h2[j], 0.f);
    float h3[16];
    #pragma unroll
    for (int j = 0; j < 16; ++j) h3[j] = s_b3[j];
    #pragma unroll
    for (int i = 0; i < 16; ++i) {
        const float4 q0 = *(const float4*)&s_w3[i][0];
        const float4 q1 = *(const float4*)&s_w3[i][4];
        const float4 q2 = *(const float4*)&s_w3[i][8];
        const float4 q3 = *(const float4*)&s_w3[i][12];
        h3[0]  = fmaf(h2[i], q0.x, h3[0]);  h3[1]  = fmaf(h2[i], q0.y, h3[1]);
        h3[2]  = fmaf(h2[i], q0.z, h3[2]);  h3[3]  = fmaf(h2[i], q0.w, h3[3]);
        h3[4]  = fmaf(h2[i], q1.x, h3[4]);  h3[5]  = fmaf(h2[i], q1.y, h3[5]);
        h3[6]  = fmaf(h2[i], q1.z, h3[6]);  h3[7]  = fmaf(h2[i], q1.w, h3[7]);
        h3[8]  = fmaf(h2[i], q2.x, h3[8]);  h3[9]  = fmaf(h2[i], q2.y, h3[9]);
        h3[10] = fmaf(h2[i], q2.z, h3[10]); h3[11] = fmaf(h2[i], q2.w, h3[11]);
        h3[12] = fmaf(h2[i], q3.x, h3[12]); h3[13] = fmaf(h2[i], q3.y, h3[13]);
        h3[14] = fmaf(h2[i], q3.z, h3[14]); h3[15] = fmaf(h2[i], q3.w, h3[15]);
    }
    float4* o = (float4*)(h3g + (size_t)task * 16);
    o[0] = make_float4(fmaxf(h3[0],0.f),  fmaxf(h3[1],0.f),  fmaxf(h3[2],0.f),  fmaxf(h3[3],0.f));
    o[1] = make_float4(fmaxf(h3[4],0.f),  fmaxf(h3[5],0.f),  fmaxf(h3[6],0.f),  fmaxf(h3[7],0.f));
    o[2] = make_float4(fmaxf(h3[8],0.f),  fmaxf(h3[9],0.f),  fmaxf(h3[10],0.f), fmaxf(h3[11],0.f));
    o[3] = make_float4(fmaxf(h3[12],0.f), fmaxf(h3[13],0.f), fmaxf(h3[14],0.f), fmaxf(h3[15],0.f));
}

// ============ stage B: gather + outer-product + MFMA, 1 wave = 16 points ============
__global__ __launch_bounds__(64) void gemm_kernel(
    const float* __restrict__ inp, const int* __restrict__ indices,
    const float* __restrict__ h3g, const unsigned short* __restrict__ Wt,
    const float* __restrict__ bias, float* __restrict__ out)
{
    __shared__ int s_idx[P * KK];               // 1 KB
    __shared__ unsigned short s_fb[P][512];     // 16 KB bf16, one k''-half, XOR-swizzled
    const int lane = threadIdx.x;
    const int pt0  = blockIdx.x * P;
    const int b    = pt0 >> 13;

    *(int4*)&s_idx[lane * 4] = *(const int4*)&indices[(size_t)pt0 * KK + lane * 4];
    __threadfence_block();

    // ---- phase 2: f[p][cin][m], lane = cin; half-1 -> LDS, half-2 -> hold regs ----
    uint4 hold[16];
    #pragma unroll
    for (int p2 = 0; p2 < P; ++p2) {
        float accf[16];
        #pragma unroll
        for (int m = 0; m < 16; ++m) accf[m] = 0.f;
        const float* hbase = h3g + ((size_t)(pt0 + p2) * KK) * 16;
        #pragma unroll
        for (int k = 0; k < KK; ++k) {
            const int id = s_idx[p2 * KK + k];
            const float fv = inp[((size_t)(b * NN + id)) * 64 + lane];
            const float4 q0 = *(const float4*)(hbase + k * 16 + 0);
            const float4 q1 = *(const float4*)(hbase + k * 16 + 4);
            const float4 q2 = *(const float4*)(hbase + k * 16 + 8);
            const float4 q3 = *(const float4*)(hbase + k * 16 + 12);
            accf[0]  = fmaf(fv, q0.x, accf[0]);  accf[1]  = fmaf(fv, q0.y, accf[1]);
            accf[2]  = fmaf(fv, q0.z, accf[2]);  accf[3]  = fmaf(fv, q0.w, accf[3]);
            accf[4]  = fmaf(fv, q1.x, accf[4]);  accf[5]  = fmaf(fv, q1.y, accf[5]);
            accf[6]  = fmaf(fv, q1.z, accf[6]);  accf[7]  = fmaf(fv, q1.w, accf[7]);
            accf[8]  = fmaf(fv, q2.x, accf[8]);  accf[9]  = fmaf(fv, q2.y, accf[9]);
            accf[10] = fmaf(fv, q2.z, accf[10]); accf[11] = fmaf(fv, q2.w, accf[11]);
            accf[12] = fmaf(fv, q3.x, accf[12]); accf[13] = fmaf(fv, q3.y, accf[13]);
            accf[14] = fmaf(fv, q3.z, accf[14]); accf[15] = fmaf(fv, q3.w, accf[15]);
        }
        unsigned int pk[8];
        #pragma unroll
        for (int i = 0; i < 8; ++i)
            pk[i] = pack_bf2(accf[2 * i], accf[2 * i + 1]);
        hold[p2] = make_uint4(pk[4], pk[5], pk[6], pk[7]);
        char* fbb = (char*)s_fb;
        const unsigned int off =
            ((unsigned)(p2 * 1024 + lane * 16)) ^ ((unsigned)(p2 & 7) << 4);
        *(uint4*)(fbb + off) = make_uint4(pk[0], pk[1], pk[2], pk[3]);
    }
    __threadfence_block();

    // ---- phase 3: 2 halves x 16 k-steps x 4 cout-tiles ----
    const int arow = lane & 15;          // A row = point; B col = cout_local
    const int hi   = lane >> 4;
    const unsigned int abase = (unsigned)arow * 1024u + (unsigned)hi * 16u;
    const unsigned int xr    = (unsigned)(arow & 7) << 4;
    const char* fbb = (const char*)s_fb;
    const unsigned short* wb0 = Wt + (size_t)( 0 + arow) * 1024 + hi * 8;
    const unsigned short* wb1 = Wt + (size_t)(16 + arow) * 1024 + hi * 8;
    const unsigned short* wb2 = Wt + (size_t)(32 + arow) * 1024 + hi * 8;
    const unsigned short* wb3 = Wt + (size_t)(48 + arow) * 1024 + hi * 8;
    f32x4 acc0 = {0.f,0.f,0.f,0.f}, acc1 = {0.f,0.f,0.f,0.f};
    f32x4 acc2 = {0.f,0.f,0.f,0.f}, acc3 = {0.f,0.f,0.f,0.f};
    #pragma unroll
    for (int kk = 0; kk < 16; ++kk) {
        const bf16x8 av = *(const bf16x8*)(fbb + ((abase + (unsigned)kk * 64u) ^ xr));
        acc0 = __builtin_amdgcn_mfma_f32_16x16x32_bf16(av, *(const bf16x8*)(wb0 + kk * 32), acc0, 0, 0, 0);
        acc1 = __builtin_amdgcn_mfma_f32_16x16x32_bf16(av, *(const bf16x8*)(wb1 + kk * 32), acc1, 0, 0, 0);
        acc2 = __builtin_amdgcn_mfma_f32_16x16x32_bf16(av, *(const bf16x8*)(wb2 + kk * 32), acc2, 0, 0, 0);
        acc3 = __builtin_amdgcn_mfma_f32_16x16x32_bf16(av, *(const bf16x8*)(wb3 + kk * 32), acc3, 0, 0, 0);
    }
    __threadfence_block();               // half-1 reads retired (in-order DS) + compiler fence
    {
        char* fbw = (char*)s_fb;
        #pragma unroll
        for (int p2 = 0; p2 < P; ++p2) {
            const unsigned int off =
                ((unsigned)(p2 * 1024 + lane * 16)) ^ ((unsigned)(p2 & 7) << 4);
            *(uint4*)(fbw + off) = hold[p2];
        }
    }
    __threadfence_block();
    #pragma unroll
    for (int kk = 0; kk < 16; ++kk) {
        const bf16x8 av = *(const bf16x8*)(fbb + ((abase + (unsigned)kk * 64u) ^ xr));
        acc0 = __builtin_amdgcn_mfma_f32_16x16x32_bf16(av, *(const bf16x8*)(wb0 + 512 + kk * 32), acc0, 0, 0, 0);
        acc1 = __builtin_amdgcn_mfma_f32_16x16x32_bf16(av, *(const bf16x8*)(wb1 + 512 + kk * 32), acc1, 0, 0, 0);
        acc2 = __builtin_amdgcn_mfma_f32_16x16x32_bf16(av, *(const bf16x8*)(wb2 + 512 + kk * 32), acc2, 0, 0, 0);
        acc3 = __builtin_amdgcn_mfma_f32_16x16x32_bf16(av, *(const bf16x8*)(wb3 + 512 + kk * 32), acc3, 0, 0, 0);
    }

    const float bv0 = bias[ 0 + arow];
    const float bv1 = bias[16 + arow];
    const float bv2 = bias[32 + arow];
    const float bv3 = bias[48 + arow];
    #pragma unroll
    for (int r = 0; r < 4; ++r) {
        float* orow = out + ((size_t)(pt0 + hi * 4 + r)) * 64;
        orow[ 0 + arow] = acc0[r] + bv0;
        orow[16 + arow] = acc1[r] + bv1;
        orow[32 + arow] = acc2[r] + bv2;
        orow[48 + arow] = acc3[r] + bv3;
    }
}

// ================= fallback: proven round-6 monolith =================
__global__ __launch_bounds__(256, 2) void ptconv_fused(
    const float* __restrict__ inp, const float* __restrict__ points,
    const float* __restrict__ next_pts, const int* __restrict__ indices,
    const unsigned short* __restrict__ Wt, const float* __restrict__ A1f,
    const float* __restrict__ bias,
    const float* __restrict__ l2w, const float* __restrict__ l2b,
    const float* __restrict__ l3w, const float* __restrict__ l3b,
    float* __restrict__ out)
{
    const int t    = threadIdx.x;
    const int lane = t & 63;
    const int w    = t >> 6;
    const int pt0  = blockIdx.x * P;
    const int b    = pt0 >> 13;

    __shared__ float s_A1[32][4];
    __shared__ float s_w2[32][16];
    __shared__ float s_w3[16][16];
    __shared__ float s_b2[16], s_b3[16];
    __shared__ int   s_idx[P][KK];
    __shared__ float s_nxt[P][3];
    __shared__ float s_h3[P][264];
    __shared__ unsigned short s_fb[P][512];

    if (t < 128) ((float*)s_A1)[t] = A1f[t];
    for (int i = t; i < 512; i += 256) ((float*)s_w2)[i] = l2w[i];
    if (t < 256) ((float*)s_w3)[t] = l3w[t];
    if (t < 16)  { s_b2[t] = l2b[t]; s_b3[t] = l3b[t]; }
    ((int*)s_idx)[t] = indices[(size_t)pt0 * KK + t];
    if (t < P * 3) ((float*)s_nxt)[t] = next_pts[(size_t)pt0 * 3 + t];
    __syncthreads();

    {
        const int p = t >> 4, k = t & 15;
        const int id = s_idx[p][k];
        const float* pp = points + ((size_t)(b * NN + id)) * 3;
        const float px = pp[0] - s_nxt[p][0];
        const float py = pp[1] - s_nxt[p][1];
        const float pz = pp[2] - s_nxt[p][2];
        float h1[32];
        #pragma unroll
        for (int j = 0; j < 32; ++j) {
            const float4 a = *(const float4*)&s_A1[j][0];
            h1[j] = fmaxf(fmaf(px, a.x, fmaf(py, a.y, fmaf(pz, a.z, a.w))), 0.f);
        }
        float h2[16];
        #pragma unroll
        for (int j = 0; j < 16; ++j) h2[j] = s_b2[j];
        #pragma unroll
        for (int i = 0; i < 32; ++i) {
            const float4 q0 = *(const float4*)&s_w2[i][0];
            const float4 q1 = *(const float4*)&s_w2[i][4];
            const float4 q2 = *(const float4*)&s_w2[i][8];
            const float4 q3 = *(const float4*)&s_w2[i][12];
            h2[0]  = fmaf(h1[i], q0.x, h2[0]);  h2[1]  = fmaf(h1[i], q0.y, h2[1]);
            h2[2]  = fmaf(h1[i], q0.z, h2[2]);  h2[3]  = fmaf(h1[i], q0.w, h2[3]);
            h2[4]  = fmaf(h1[i], q1.x, h2[4]);  h2[5]  = fmaf(h1[i], q1.y, h2[5]);
            h2[6]  = fmaf(h1[i], q1.z, h2[6]);  h2[7]  = fmaf(h1[i], q1.w, h2[7]);
            h2[8]  = fmaf(h1[i], q2.x, h2[8]);  h2[9]  = fmaf(h1[i], q2.y, h2[9]);
            h2[10] = fmaf(h1[i], q2.z, h2[10]); h2[11] = fmaf(h1[i], q2.w, h2[11]);
            h2[12] = fmaf(h1[i], q3.x, h2[12]); h2[13] = fmaf(h1[i], q3.y, h2[13]);
            h2[14] = fmaf(h1[i], q3.z, h2[14]); h2[15] = fmaf(h1[i], q3.w, h2[15]);
        }
        #pragma unroll
        for (int j = 0; j < 16; ++j) h2[j] = fmaxf(h2[j], 0.f);
        float h3[16];
        #pragma unroll
        for (int j = 0; j < 16; ++j) h3[j] = s_b3[j];
        #pragma unroll
        for (int i = 0; i < 16; ++i) {
            const float4 q0 = *(const float4*)&s_w3[i][0];
            const float4 q1 = *(const float4*)&s_w3[i][4];
            const float4 q2 = *(const float4*)&s_w3[i][8];
            const float4 q3 = *(const float4*)&s_w3[i][12];
            h3[0]  = fmaf(h2[i], q0.x, h3[0]);  h3[1]  = fmaf(h2[i], q0.y, h3[1]);
            h3[2]  = fmaf(h2[i], q0.z, h3[2]);  h3[3]  = fmaf(h2[i], q0.w, h3[3]);
            h3[4]  = fmaf(h2[i], q1.x, h3[4]);  h3[5]  = fmaf(h2[i], q1.y, h3[5]);
            h3[6]  = fmaf(h2[i], q1.z, h3[6]);  h3[7]  = fmaf(h2[i], q1.w, h3[7]);
            h3[8]  = fmaf(h2[i], q2.x, h3[8]);  h3[9]  = fmaf(h2[i], q2.y, h3[9]);
            h3[10] = fmaf(h2[i], q2.z, h3[10]); h3[11] = fmaf(h2[i], q2.w, h3[11]);
            h3[12] = fmaf(h2[i], q3.x, h3[12]); h3[13] = fmaf(h2[i], q3.y, h3[13]);
            h3[14] = fmaf(h2[i], q3.z, h3[14]); h3[15] = fmaf(h2[i], q3.w, h3[15]);
        }
        #pragma unroll
        for (int m = 0; m < 16; ++m)
            s_h3[p][k * 16 + ((m + k) & 15)] = fmaxf(h3[m], 0.f);
    }
    __syncthreads();

    uint4 hold[4];
    {
        #pragma unroll
        for (int j = 0; j < 4; ++j) {
            const int p2 = w * 4 + j;
            float accf[16];
            #pragma unroll
            for (int m = 0; m < 16; ++m) accf[m] = 0.f;
            #pragma unroll
            for (int k = 0; k < 16; ++k) {
                const int id = s_idx[p2][k];
                const float fv = inp[((size_t)(b * NN + id)) * 64 + lane];
                const float* hr = &s_h3[p2][k * 16];
                float hv[16];
                #pragma unroll
                for (int q = 0; q < 4; ++q) {
                    const float4 qq = *(const float4*)(hr + q * 4);
                    hv[q * 4 + 0] = qq.x; hv[q * 4 + 1] = qq.y;
                    hv[q * 4 + 2] = qq.z; hv[q * 4 + 3] = qq.w;
                }
                #pragma unroll
                for (int m = 0; m < 16; ++m)
                    accf[m] = fmaf(fv, hv[(m + k) & 15], accf[m]);
            }
            unsigned int pk[8];
            #pragma unroll
            for (int i = 0; i < 8; ++i)
                pk[i] = pack_bf2(accf[2 * i], accf[2 * i + 1]);
            hold[j] = make_uint4(pk[4], pk[5], pk[6], pk[7]);
            char* fbb = (char*)s_fb;
            const unsigned int off =
                ((unsigned)(p2 * 1024 + lane * 16)) ^ ((unsigned)(p2 & 7) << 4);
            *(uint4*)(fbb + off) = make_uint4(pk[0], pk[1], pk[2], pk[3]);
        }
    }
    __syncthreads();

    {
        const int arow = lane & 15;
        const int hi   = lane >> 4;
        const unsigned int abase = (unsigned)arow * 1024u + (unsigned)hi * 16u;
        const unsigned int xr    = (unsigned)(arow & 7) << 4;
        const unsigned short* wb = Wt + (size_t)(w * 16 + arow) * 1024 + hi * 8;
        const char* fbb = (const char*)s_fb;
        f32x4 acc = {0.f, 0.f, 0.f, 0.f};
        #pragma unroll
        for (int kk = 0; kk < 16; ++kk) {
            const bf16x8 av = *(const bf16x8*)(fbb + ((abase + (unsigned)kk * 64u) ^ xr));
            const bf16x8 bv = *(const bf16x8*)(wb + kk * 32);
            acc = __builtin_amdgcn_mfma_f32_16x16x32_bf16(av, bv, acc, 0, 0, 0);
        }
        __syncthreads();
        #pragma unroll
        for (int j = 0; j < 4; ++j) {
            const int p2 = w * 4 + j;
            char* fbw = (char*)s_fb;
            const unsigned int off =
                ((unsigned)(p2 * 1024 + lane * 16)) ^ ((unsigned)(p2 & 7) << 4);
            *(uint4*)(fbw + off) = hold[j];
        }
        __syncthreads();
        #pragma unroll
        for (int kk = 0; kk < 16; ++kk) {
            const bf16x8 av = *(const bf16x8*)(fbb + ((abase + (unsigned)kk * 64u) ^ xr));
            const bf16x8 bv = *(const bf16x8*)(wb + 512 + kk * 32);
            acc = __builtin_amdgcn_mfma_f32_16x16x32_bf16(av, bv, acc, 0, 0, 0);
        }
        const float bvs = bias[w * 16 + arow];
        #pragma unroll
        for (int r = 0; r < 4; ++r)
            out[((size_t)(pt0 + hi * 4 + r)) * 64 + w * 16 + arow] = acc[r] + bvs;
    }
}

extern "C" void kernel_launch(void* const* d_in, const int* in_sizes, int n_in,
                              void* d_out, int out_size, void* d_ws, size_t ws_size,
                              hipStream_t stream) {
    const float* inp      = (const float*)d_in[0];
    const float* points   = (const float*)d_in[1];
    const float* next_pts = (const float*)d_in[2];
    const int*   indices  = (const int*)  d_in[3];
    const float* weight   = (const float*)d_in[4];
    const float* bias     = (const float*)d_in[5];
    const float* centers  = (const float*)d_in[6];
    const float* l1w      = (const float*)d_in[7];
    const float* l1b      = (const float*)d_in[8];
    const float* l2w      = (const float*)d_in[9];
    const float* l2b      = (const float*)d_in[10];
    const float* l3w      = (const float*)d_in[11];
    const float* l3b      = (const float*)d_in[12];
    float* outp = (float*)d_out;

    unsigned short* Wt  = (unsigned short*)d_ws;            // 128 KB
    float*          A1f = (float*)((char*)d_ws + 131072);   // 512 B
    const size_t H3_OFF = (size_t)1 << 20;                  // 1 MB
    const size_t need   = H3_OFF + (size_t)BB * NN * KK * 16 * 4;  // 1 MB + 32 MB

    prep_w<<<256, 256, 0, stream>>>(weight, Wt);
    prep_fold<<<1, 32, 0, stream>>>(l1w, l1b, centers, A1f);

    if (ws_size >= need) {
        float* h3g = (float*)((char*)d_ws + H3_OFF);
        mlp_kernel<<<2048, 256, 0, stream>>>(points, next_pts, indices, A1f,
                                             l2w, l2b, l3w, l3b, h3g);
        gemm_kernel<<<2048, 64, 0, stream>>>(inp, indices, h3g, Wt, bias, outp);
    } else {
        ptconv_fused<<<2048, 256, 0, stream>>>(inp, points, next_pts, indices,
                                               Wt, A1f, bias,
                                               l2w, l2b, l3w, l3b, outp);
    }
}